// Round 12
// baseline (16323.917 us; speedup 1.0000x reference)
//
#include <hip/hip_runtime.h>
#include <cstddef>
#include <cstdint>

#define T_LEN 4096
#define FDIM  1024
#define H2DIM 1024
#define GDIM  4096   // 4*H2

#define NEGV (-10000.0f)
#define START_TAG 2
#define STOP_TAG 3

// ---- workspace layout (bytes) ----
#define XP_OFF      ((size_t)0)
#define XP_BYTES    ((size_t)2 * T_LEN * GDIM * 4)          // 134,217,728
#define HIST_OFF    (XP_OFF + XP_BYTES)
#define HIST_BYTES  ((size_t)T_LEN * 2048 * 4)              // 33,554,432
#define FEATS_OFF   (HIST_OFF + HIST_BYTES)
#define FEATS_BYTES ((size_t)T_LEN * 4 * 4)
#define SLOTS_OFF   (FEATS_OFF + FEATS_BYTES)
#define SLOTS_BYTES ((size_t)2 * 2 * 1024 * 8)              // parity x dir x unit, u64
#define WS_NEED     (SLOTS_OFF + SLOTS_BYTES)

// bf16 staging buffers live INSIDE the hist region (dead until the scan runs;
// the gemm finishes reading them before lstm_scan overwrites hist).
#define XB_OFF      (HIST_OFF)                               // 8 MB
#define WBF_OFF     (HIST_OFF + (size_t)8  * 1024 * 1024)    // 8 MB
#define WBB_OFF     (HIST_OFF + (size_t)16 * 1024 * 1024)    // 8 MB

__device__ __forceinline__ float sigm(float x) { return 1.0f / (1.0f + expf(-x)); }

__device__ __forceinline__ unsigned short f2bf(float f) {
    unsigned u = __float_as_uint(f);
    return (unsigned short)((u + 0x7FFFu + ((u >> 16) & 1u)) >> 16);   // RNE
}

// compose two 4-element tag maps packed as u32 (byte c = map(c), values 0..3)
__device__ __forceinline__ unsigned compose4(unsigned A, unsigned B) {
    unsigned r = 0;
    #pragma unroll
    for (int c = 0; c < 4; ++c) {
        const unsigned b = (B >> (8 * c)) & 3u;
        const unsigned a = (A >> (8 * b)) & 3u;
        r |= a << (8 * c);
    }
    return r;
}

typedef short  bf16x8 __attribute__((ext_vector_type(8)));
typedef float  f32x4  __attribute__((ext_vector_type(4)));

// ============================================================================
// Kernel 0: fp32 -> bf16 (RNE), vectorized grid-stride
// ============================================================================
__global__ __launch_bounds__(256)
void conv_bf16(const float* __restrict__ src, unsigned short* __restrict__ dst, int n4)
{
    int i = blockIdx.x * 256 + threadIdx.x;
    const int stride = gridDim.x * 256;
    for (; i < n4; i += stride) {
        const float4 v = ((const float4*)src)[i];
        ushort4 o;
        o.x = f2bf(v.x); o.y = f2bf(v.y); o.z = f2bf(v.z); o.w = f2bf(v.w);
        ((ushort4*)dst)[i] = o;
    }
}

// ============================================================================
// Kernel 1: bf16 MFMA input GEMM, LDS-tiled (R11, unchanged; absmax=0).
// ============================================================================
__global__ __launch_bounds__(256)
void xp_gemm_mfma(const unsigned short* __restrict__ xb,
                  const unsigned short* __restrict__ wb_f,
                  const unsigned short* __restrict__ wb_b,
                  const float* __restrict__ bi_f, const float* __restrict__ bh_f,
                  const float* __restrict__ bi_b, const float* __restrict__ bh_b,
                  float* __restrict__ xp)
{
    __shared__ unsigned short As[128][40];   // 10,240 B
    __shared__ unsigned short Bs[128][40];   // 10,240 B

    const int tid  = threadIdx.x;
    const int lane = tid & 63;
    const int wv   = tid >> 6;           // wave 0..3
    const int wr   = (wv >> 1) * 64;     // quadrant row offset
    const int wc   = (wv & 1) * 64;      // quadrant col offset
    const int dir  = blockIdx.y;

    const int bid = blockIdx.x;
    const int swz = (bid & 7) * 128 + (bid >> 3);
    const int t0  = (swz >> 5) * 128;
    const int j0  = (swz & 31) * 128;

    const unsigned short* __restrict__ wb = dir ? wb_b : wb_f;
    const float* __restrict__ bi = dir ? bi_b : bi_f;
    const float* __restrict__ bh = dir ? bh_b : bh_f;

    const int r  = lane & 15;
    const int kg = lane >> 4;            // k-group 0..3

    const int srow = tid >> 2;           // 0..63
    const int skp  = (tid & 3) * 8;      // 0,8,16,24

    const int tgA0 = t0 + srow;
    const int tgA1 = t0 + srow + 64;
    const size_t arow0 = (size_t)(dir ? (T_LEN - 1 - tgA0) : tgA0) * FDIM;
    const size_t arow1 = (size_t)(dir ? (T_LEN - 1 - tgA1) : tgA1) * FDIM;
    const size_t brow0 = (size_t)(j0 + srow) * FDIM;
    const size_t brow1 = (size_t)(j0 + srow + 64) * FDIM;

    f32x4 acc[4][4];
    #pragma unroll
    for (int sm = 0; sm < 4; ++sm)
        #pragma unroll
        for (int sn = 0; sn < 4; ++sn)
            acc[sm][sn] = (f32x4){0.f, 0.f, 0.f, 0.f};

    for (int kb = 0; kb < FDIM; kb += 32) {
        __syncthreads();
        *(bf16x8*)&As[srow     ][skp] = *(const bf16x8*)&xb[arow0 + kb + skp];
        *(bf16x8*)&As[srow + 64][skp] = *(const bf16x8*)&xb[arow1 + kb + skp];
        *(bf16x8*)&Bs[srow     ][skp] = *(const bf16x8*)&wb[brow0 + kb + skp];
        *(bf16x8*)&Bs[srow + 64][skp] = *(const bf16x8*)&wb[brow1 + kb + skp];
        __syncthreads();

        bf16x8 a[4], b[4];
        #pragma unroll
        for (int s = 0; s < 4; ++s) {
            a[s] = *(const bf16x8*)&As[wr + s * 16 + r][kg * 8];
            b[s] = *(const bf16x8*)&Bs[wc + s * 16 + r][kg * 8];
        }
        #pragma unroll
        for (int sm = 0; sm < 4; ++sm)
            #pragma unroll
            for (int sn = 0; sn < 4; ++sn)
                acc[sm][sn] = __builtin_amdgcn_mfma_f32_16x16x32_bf16(
                                  a[sm], b[sn], acc[sm][sn], 0, 0, 0);
    }

    float* __restrict__ xpd = xp + (size_t)dir * T_LEN * GDIM;
    #pragma unroll
    for (int sn = 0; sn < 4; ++sn) {
        const int col  = j0 + wc + sn * 16 + r;
        const float bv = bi[col] + bh[col];
        #pragma unroll
        for (int sm = 0; sm < 4; ++sm) {
            #pragma unroll
            for (int j = 0; j < 4; ++j) {
                const int row = t0 + wr + sm * 16 + kg * 4 + j;
                xpd[(size_t)row * GDIM + col] = acc[sm][sn][j] + bv;
            }
        }
    }
}

// ============================================================================
// Kernel 2: cooperative persistent bidirectional LSTM scan.
// R10/R11 structure; exchange updated: (1) publish slot BEFORE hist store,
// (2) poll is 2-deep PIPELINED (issue next generation's 4 loads before
// checking the current generation; no per-slot latching needed -- tag is
// monotone within a parity window, so any generation with all 4 tags == want
// is self-consistent), no s_sleep (R7/R8 showed sleep and poll rate are
// neutral; discovery cadence drops from latency+sleep+latency to ~latency).
// ============================================================================
__global__ __launch_bounds__(256, 1)
void lstm_scan(const float* __restrict__ xp,
               const float* __restrict__ h0,
               const float* __restrict__ c0,
               const float* __restrict__ whh_f,
               const float* __restrict__ whh_b,
               float* __restrict__ hist,
               unsigned long long* __restrict__ slots)
{
    __shared__ float wsl[32][1024];   // 131072 B
    __shared__ float hbuf[1024];      //   4096 B
    __shared__ float gsh[32];

    const int tid = threadIdx.x;
    const int b   = blockIdx.x;
    const int dir = b & 1;            // XCD swizzle: fwd on even, bwd on odd
    const int bi  = b >> 1;
    const int u0  = bi * 8;
    const int rg  = tid >> 5;   // 0..7  (row group: 4 rows)
    const int kc  = tid & 31;   // 0..31 (k chunk)
    const int lrb = rg * 4;

    const float* __restrict__ whh = dir ? whh_b : whh_f;
    const size_t xpbase = (size_t)dir * T_LEN * GDIM;

    for (int lr = 0; lr < 32; ++lr) {
        const int grow = ((lr >> 3) << 10) + u0 + (lr & 7);
        *(float4*)&wsl[lr][tid * 4] = *(const float4*)&whh[(size_t)grow * H2DIM + tid * 4];
    }
    *(float4*)&hbuf[tid * 4] = *(const float4*)&h0[dir * H2DIM + tid * 4];
    float creg = 0.f;
    if (tid < 8) creg = c0[dir * H2DIM + u0 + tid];

    int grows[4];
    #pragma unroll
    for (int j = 0; j < 4; ++j) {
        const int lr = lrb + j;
        grows[j] = ((lr >> 3) << 10) + u0 + (lr & 7);
    }
    float xpc[4] = {0.f, 0.f, 0.f, 0.f};
    if (kc == 0) {
        #pragma unroll
        for (int j = 0; j < 4; ++j) xpc[j] = xp[xpbase + grows[j]];
    }
    __syncthreads();

    int budget = 4000000;

    for (int t = 0; t < T_LEN; ++t) {
        float xpn[4] = {0.f, 0.f, 0.f, 0.f};
        const int tnx = (t + 1 < T_LEN) ? (t + 1) : t;
        if (kc == 0) {
            #pragma unroll
            for (int j = 0; j < 4; ++j) xpn[j] = xp[xpbase + (size_t)tnx * GDIM + grows[j]];
        }

        float p0 = 0.f, p1 = 0.f, p2 = 0.f, p3 = 0.f;
        #pragma unroll
        for (int s = 0; s < 8; ++s) {
            const int ko = s * 128 + kc * 4;
            const float4 hv = *(const float4*)&hbuf[ko];
            const float4 w0 = *(const float4*)&wsl[lrb + 0][ko];
            const float4 w1 = *(const float4*)&wsl[lrb + 1][ko];
            const float4 w2 = *(const float4*)&wsl[lrb + 2][ko];
            const float4 w3 = *(const float4*)&wsl[lrb + 3][ko];
            p0 += w0.x*hv.x + w0.y*hv.y + w0.z*hv.z + w0.w*hv.w;
            p1 += w1.x*hv.x + w1.y*hv.y + w1.z*hv.z + w1.w*hv.w;
            p2 += w2.x*hv.x + w2.y*hv.y + w2.z*hv.z + w2.w*hv.w;
            p3 += w3.x*hv.x + w3.y*hv.y + w3.z*hv.z + w3.w*hv.w;
        }
        #pragma unroll
        for (int m = 16; m >= 1; m >>= 1) {
            p0 += __shfl_xor(p0, m);
            p1 += __shfl_xor(p1, m);
            p2 += __shfl_xor(p2, m);
            p3 += __shfl_xor(p3, m);
        }
        if (kc == 0) {
            gsh[lrb + 0] = p0 + xpc[0];
            gsh[lrb + 1] = p1 + xpc[1];
            gsh[lrb + 2] = p2 + xpc[2];
            gsh[lrb + 3] = p3 + xpc[3];
        }
        __syncthreads();

        // LSTM cell on 8 threads -- wave-coalesced publish, slot store FIRST
        if (tid < 8) {
            const float gi = gsh[tid];
            const float gf = gsh[8 + tid];
            const float gg = gsh[16 + tid];
            const float go = gsh[24 + tid];
            const float c  = sigm(gf) * creg + sigm(gi) * tanhf(gg);
            const float h  = sigm(go) * tanhf(c);
            creg = c;
            const unsigned long long pack =
                ((unsigned long long)(unsigned)(t + 1) << 32) |
                (unsigned long long)__float_as_uint(h);
            __hip_atomic_store(&slots[((size_t)((t + 1) & 1) * 2 + dir) * H2DIM + u0 + tid],
                               pack, __ATOMIC_RELAXED, __HIP_MEMORY_SCOPE_AGENT);
            const int tg = dir ? (T_LEN - 1 - t) : t;
            hist[(size_t)tg * 2048 + dir * H2DIM + u0 + tid] = h;
        }

        // 2-deep pipelined poll: issue gen n+1 before checking gen n
        if (t + 1 < T_LEN) {
            const unsigned want = (unsigned)(t + 1);
            unsigned long long* sb = &slots[((size_t)((t + 1) & 1) * 2 + dir) * H2DIM + tid * 4];
            unsigned long long c0v, c1v, c2v, c3v;
            c0v = __hip_atomic_load(&sb[0], __ATOMIC_RELAXED, __HIP_MEMORY_SCOPE_AGENT);
            c1v = __hip_atomic_load(&sb[1], __ATOMIC_RELAXED, __HIP_MEMORY_SCOPE_AGENT);
            c2v = __hip_atomic_load(&sb[2], __ATOMIC_RELAXED, __HIP_MEMORY_SCOPE_AGENT);
            c3v = __hip_atomic_load(&sb[3], __ATOMIC_RELAXED, __HIP_MEMORY_SCOPE_AGENT);
            for (;;) {
                const unsigned long long n0 = __hip_atomic_load(&sb[0], __ATOMIC_RELAXED, __HIP_MEMORY_SCOPE_AGENT);
                const unsigned long long n1 = __hip_atomic_load(&sb[1], __ATOMIC_RELAXED, __HIP_MEMORY_SCOPE_AGENT);
                const unsigned long long n2 = __hip_atomic_load(&sb[2], __ATOMIC_RELAXED, __HIP_MEMORY_SCOPE_AGENT);
                const unsigned long long n3 = __hip_atomic_load(&sb[3], __ATOMIC_RELAXED, __HIP_MEMORY_SCOPE_AGENT);
                if ((unsigned)(c0v >> 32) == want && (unsigned)(c1v >> 32) == want &&
                    (unsigned)(c2v >> 32) == want && (unsigned)(c3v >> 32) == want) break;
                if (--budget <= 0) break;                // hang-proof bail
                c0v = n0; c1v = n1; c2v = n2; c3v = n3;
            }
            float4 hv;
            hv.x = __uint_as_float((unsigned)c0v);
            hv.y = __uint_as_float((unsigned)c1v);
            hv.z = __uint_as_float((unsigned)c2v);
            hv.w = __uint_as_float((unsigned)c3v);
            *(float4*)&hbuf[tid * 4] = hv;
        }
        __syncthreads();
        if (kc == 0) { xpc[0] = xpn[0]; xpc[1] = xpn[1]; xpc[2] = xpn[2]; xpc[3] = xpn[3]; }
    }
}

// ============================================================================
// Kernel 3: feats[t][n] = dot(hist[t], w_tag[n]) + b_tag[n]
// ============================================================================
__global__ __launch_bounds__(256)
void feats_kernel(const float* __restrict__ hist,
                  const float* __restrict__ w_tag,
                  const float* __restrict__ b_tag,
                  float* __restrict__ feats)
{
    const int t = blockIdx.x;
    const int tid = threadIdx.x;
    const float* __restrict__ hrow = hist + (size_t)t * 2048 + tid * 8;
    const float4 ha = *(const float4*)&hrow[0];
    const float4 hb = *(const float4*)&hrow[4];
    float p[4];
    #pragma unroll
    for (int n = 0; n < 4; ++n) {
        const float* __restrict__ wr = w_tag + n * 2048 + tid * 8;
        const float4 wa = *(const float4*)&wr[0];
        const float4 wb = *(const float4*)&wr[4];
        p[n] = ha.x*wa.x + ha.y*wa.y + ha.z*wa.z + ha.w*wa.w
             + hb.x*wb.x + hb.y*wb.y + hb.z*wb.z + hb.w*wb.w;
    }
    #pragma unroll
    for (int m = 32; m >= 1; m >>= 1) {
        #pragma unroll
        for (int n = 0; n < 4; ++n) p[n] += __shfl_down(p[n], m);
    }
    __shared__ float red[4][4];
    const int wv = tid >> 6;
    if ((tid & 63) == 0) {
        #pragma unroll
        for (int n = 0; n < 4; ++n) red[n][wv] = p[n];
    }
    __syncthreads();
    if (tid < 4)
        feats[(size_t)t * 4 + tid] = red[tid][0] + red[tid][1] + red[tid][2] + red[tid][3] + b_tag[tid];
}

// ============================================================================
// Kernel 4: Viterbi v2 (R10, unchanged; absmax=0 verified).
// ============================================================================
__global__ __launch_bounds__(256)
void viterbi_kernel(const float* __restrict__ feats,
                    const float* __restrict__ trans,
                    float* __restrict__ out)
{
    __shared__ float fsh[T_LEN * 4];   // 64 KB
    __shared__ unsigned bp[T_LEN];     // 16 KB
    __shared__ unsigned lmap[256];
    __shared__ unsigned smap[256];
    __shared__ int bestsh;
    const int tid = threadIdx.x;
    for (int i = tid; i < T_LEN; i += 256)
        *(float4*)&fsh[i * 4] = *(const float4*)&feats[(size_t)i * 4];
    __syncthreads();

    if (tid == 0) {
        float tr[16];
        #pragma unroll
        for (int i = 0; i < 16; ++i) tr[i] = trans[i];
        float fv[4] = {NEGV, NEGV, NEGV, NEGV};
        fv[START_TAG] = 0.0f;
        for (int t0 = 0; t0 < T_LEN; t0 += 8) {
            float4 f8[8];
            #pragma unroll
            for (int j = 0; j < 8; ++j) f8[j] = *(const float4*)&fsh[(t0 + j) * 4];
            #pragma unroll
            for (int j = 0; j < 8; ++j) {
                const float ft[4] = {f8[j].x, f8[j].y, f8[j].z, f8[j].w};
                float nf[4]; unsigned pb = 0;
                #pragma unroll
                for (int n = 0; n < 4; ++n) {
                    float m = fv[0] + tr[n * 4 + 0]; int bsel = 0;
                    #pragma unroll
                    for (int p = 1; p < 4; ++p) {
                        const float s = fv[p] + tr[n * 4 + p];
                        if (s > m) { m = s; bsel = p; }
                    }
                    nf[n] = m + ft[n];
                    pb |= (unsigned)bsel << (8 * n);
                }
                bp[t0 + j] = pb;
                fv[0] = nf[0]; fv[1] = nf[1]; fv[2] = nf[2]; fv[3] = nf[3];
            }
        }
        float bm = fv[0] + tr[STOP_TAG * 4 + 0]; int best = 0;
        #pragma unroll
        for (int p = 1; p < 4; ++p) {
            const float s = fv[p] + tr[STOP_TAG * 4 + p];
            if (s > bm) { bm = s; best = p; }
        }
        out[0] = bm;
        bestsh = best;
    }
    __syncthreads();

    const int c0 = tid * 16;
    unsigned L = bp[c0 + 15];
    #pragma unroll
    for (int j = 14; j >= 0; --j) L = compose4(bp[c0 + j], L);
    lmap[tid] = L;
    __syncthreads();
    if (tid == 0) {
        unsigned acc = 0x03020100u;              // identity map
        for (int i = 255; i >= 0; --i) { smap[i] = acc; acc = compose4(lmap[i], acc); }
    }
    __syncthreads();
    unsigned carry = smap[tid];
    const int best = bestsh;
    for (int t = c0 + 15; t >= c0; --t) {
        out[1 + t] = (float)((carry >> (8 * best)) & 3u);
        carry = compose4(bp[t], carry);
    }
}

// ============================================================================
extern "C" void kernel_launch(void* const* d_in, const int* in_sizes, int n_in,
                              void* d_out, int out_size, void* d_ws, size_t ws_size,
                              hipStream_t stream) {
    const float* x      = (const float*)d_in[0];
    const float* h0     = (const float*)d_in[1];
    const float* c0     = (const float*)d_in[2];
    const float* w_ih_f = (const float*)d_in[3];
    const float* w_hh_f = (const float*)d_in[4];
    const float* b_ih_f = (const float*)d_in[5];
    const float* b_hh_f = (const float*)d_in[6];
    const float* w_ih_b = (const float*)d_in[7];
    const float* w_hh_b = (const float*)d_in[8];
    const float* b_ih_b = (const float*)d_in[9];
    const float* b_hh_b = (const float*)d_in[10];
    const float* w_tag  = (const float*)d_in[11];
    const float* b_tag  = (const float*)d_in[12];
    const float* trans  = (const float*)d_in[13];
    float* out = (float*)d_out;

    if (ws_size < WS_NEED) return;   // signature: output stays poisoned

    char* ws = (char*)d_ws;
    float* xp    = (float*)(ws + XP_OFF);
    float* hist  = (float*)(ws + HIST_OFF);
    float* feats = (float*)(ws + FEATS_OFF);
    unsigned long long* slots = (unsigned long long*)(ws + SLOTS_OFF);
    unsigned short* xb  = (unsigned short*)(ws + XB_OFF);
    unsigned short* wbf = (unsigned short*)(ws + WBF_OFF);
    unsigned short* wbb = (unsigned short*)(ws + WBB_OFF);

    hipMemsetAsync(slots, 0, SLOTS_BYTES, stream);

    // fp32 -> bf16 staging (x, w_ih_f, w_ih_b); each 4096x1024 elems -> n4 = 1M
    const int n4 = (T_LEN * FDIM) / 4;
    conv_bf16<<<1024, 256, 0, stream>>>(x,      xb,  n4);
    conv_bf16<<<1024, 256, 0, stream>>>(w_ih_f, wbf, n4);
    conv_bf16<<<1024, 256, 0, stream>>>(w_ih_b, wbb, n4);

    // LDS-tiled bf16 MFMA input GEMM
    xp_gemm_mfma<<<dim3(1024, 2), 256, 0, stream>>>(
        xb, wbf, wbb, b_ih_f, b_hh_f, b_ih_b, b_hh_b, xp);

    // scan overwrites the hist region only after the gemm has consumed xb/wb*
    void* ka[] = { (void*)&xp, (void*)&h0, (void*)&c0, (void*)&w_hh_f, (void*)&w_hh_b,
                   (void*)&hist, (void*)&slots };
    hipLaunchCooperativeKernel((void*)lstm_scan, dim3(256), dim3(256), ka, 0, stream);

    feats_kernel<<<T_LEN, 256, 0, stream>>>(hist, w_tag, b_tag, feats);
    viterbi_kernel<<<1, 256, 0, stream>>>(feats, trans, out);
}

// Round 13
// 13803.116 us; speedup vs baseline: 1.1826x; 1.1826x over previous
//
#include <hip/hip_runtime.h>
#include <cstddef>
#include <cstdint>

#define T_LEN 4096
#define FDIM  1024
#define H2DIM 1024
#define GDIM  4096   // 4*H2

#define NEGV (-10000.0f)
#define START_TAG 2
#define STOP_TAG 3

// ---- workspace layout (bytes) ----
#define XP_OFF      ((size_t)0)
#define XP_BYTES    ((size_t)2 * T_LEN * GDIM * 4)          // 134,217,728
#define HIST_OFF    (XP_OFF + XP_BYTES)
#define HIST_BYTES  ((size_t)T_LEN * 2048 * 4)              // 33,554,432
#define FEATS_OFF   (HIST_OFF + HIST_BYTES)
#define FEATS_BYTES ((size_t)T_LEN * 4 * 4)
#define SLOTS_OFF   (FEATS_OFF + FEATS_BYTES)
#define SLOTS_BYTES ((size_t)2 * 2 * 1024 * 8)              // parity x dir x unit, u64
#define WS_NEED     (SLOTS_OFF + SLOTS_BYTES)

// bf16 staging buffers live INSIDE the hist region (dead until the scan runs;
// the gemm finishes reading them before lstm_scan overwrites hist).
#define XB_OFF      (HIST_OFF)                               // 8 MB
#define WBF_OFF     (HIST_OFF + (size_t)8  * 1024 * 1024)    // 8 MB
#define WBB_OFF     (HIST_OFF + (size_t)16 * 1024 * 1024)    // 8 MB

__device__ __forceinline__ float sigm(float x) { return 1.0f / (1.0f + expf(-x)); }

__device__ __forceinline__ unsigned short f2bf(float f) {
    unsigned u = __float_as_uint(f);
    return (unsigned short)((u + 0x7FFFu + ((u >> 16) & 1u)) >> 16);   // RNE
}

// compose two 4-element tag maps packed as u32 (byte c = map(c), values 0..3)
__device__ __forceinline__ unsigned compose4(unsigned A, unsigned B) {
    unsigned r = 0;
    #pragma unroll
    for (int c = 0; c < 4; ++c) {
        const unsigned b = (B >> (8 * c)) & 3u;
        const unsigned a = (A >> (8 * b)) & 3u;
        r |= a << (8 * c);
    }
    return r;
}

typedef short  bf16x8 __attribute__((ext_vector_type(8)));
typedef float  f32x4  __attribute__((ext_vector_type(4)));

// ============================================================================
// Kernel 0: fp32 -> bf16 (RNE) for all three staging arrays in ONE launch.
// Segment s = i / n4 selects (src,dst); saves 2 kernel-launch overheads.
// ============================================================================
__global__ __launch_bounds__(256)
void conv_bf16x3(const float* __restrict__ s0, unsigned short* __restrict__ d0,
                 const float* __restrict__ s1, unsigned short* __restrict__ d1,
                 const float* __restrict__ s2, unsigned short* __restrict__ d2,
                 int n4)
{
    const int total = n4 * 3;
    int i = blockIdx.x * 256 + threadIdx.x;
    const int stride = gridDim.x * 256;
    for (; i < total; i += stride) {
        const int seg = i / n4;
        const int off = i - seg * n4;
        const float* __restrict__ src = (seg == 0) ? s0 : (seg == 1) ? s1 : s2;
        unsigned short* __restrict__ dst = (seg == 0) ? d0 : (seg == 1) ? d1 : d2;
        const float4 v = ((const float4*)src)[off];
        ushort4 o;
        o.x = f2bf(v.x); o.y = f2bf(v.y); o.z = f2bf(v.z); o.w = f2bf(v.w);
        ((ushort4*)dst)[off] = o;
    }
}

// ============================================================================
// Kernel 1: bf16 MFMA input GEMM, LDS-tiled (R11, unchanged; absmax=0).
// ============================================================================
__global__ __launch_bounds__(256)
void xp_gemm_mfma(const unsigned short* __restrict__ xb,
                  const unsigned short* __restrict__ wb_f,
                  const unsigned short* __restrict__ wb_b,
                  const float* __restrict__ bi_f, const float* __restrict__ bh_f,
                  const float* __restrict__ bi_b, const float* __restrict__ bh_b,
                  float* __restrict__ xp)
{
    __shared__ unsigned short As[128][40];   // 10,240 B
    __shared__ unsigned short Bs[128][40];   // 10,240 B

    const int tid  = threadIdx.x;
    const int lane = tid & 63;
    const int wv   = tid >> 6;           // wave 0..3
    const int wr   = (wv >> 1) * 64;     // quadrant row offset
    const int wc   = (wv & 1) * 64;      // quadrant col offset
    const int dir  = blockIdx.y;

    const int bid = blockIdx.x;
    const int swz = (bid & 7) * 128 + (bid >> 3);
    const int t0  = (swz >> 5) * 128;
    const int j0  = (swz & 31) * 128;

    const unsigned short* __restrict__ wb = dir ? wb_b : wb_f;
    const float* __restrict__ bi = dir ? bi_b : bi_f;
    const float* __restrict__ bh = dir ? bh_b : bh_f;

    const int r  = lane & 15;
    const int kg = lane >> 4;            // k-group 0..3

    const int srow = tid >> 2;           // 0..63
    const int skp  = (tid & 3) * 8;      // 0,8,16,24

    const int tgA0 = t0 + srow;
    const int tgA1 = t0 + srow + 64;
    const size_t arow0 = (size_t)(dir ? (T_LEN - 1 - tgA0) : tgA0) * FDIM;
    const size_t arow1 = (size_t)(dir ? (T_LEN - 1 - tgA1) : tgA1) * FDIM;
    const size_t brow0 = (size_t)(j0 + srow) * FDIM;
    const size_t brow1 = (size_t)(j0 + srow + 64) * FDIM;

    f32x4 acc[4][4];
    #pragma unroll
    for (int sm = 0; sm < 4; ++sm)
        #pragma unroll
        for (int sn = 0; sn < 4; ++sn)
            acc[sm][sn] = (f32x4){0.f, 0.f, 0.f, 0.f};

    for (int kb = 0; kb < FDIM; kb += 32) {
        __syncthreads();
        *(bf16x8*)&As[srow     ][skp] = *(const bf16x8*)&xb[arow0 + kb + skp];
        *(bf16x8*)&As[srow + 64][skp] = *(const bf16x8*)&xb[arow1 + kb + skp];
        *(bf16x8*)&Bs[srow     ][skp] = *(const bf16x8*)&wb[brow0 + kb + skp];
        *(bf16x8*)&Bs[srow + 64][skp] = *(const bf16x8*)&wb[brow1 + kb + skp];
        __syncthreads();

        bf16x8 a[4], b[4];
        #pragma unroll
        for (int s = 0; s < 4; ++s) {
            a[s] = *(const bf16x8*)&As[wr + s * 16 + r][kg * 8];
            b[s] = *(const bf16x8*)&Bs[wc + s * 16 + r][kg * 8];
        }
        #pragma unroll
        for (int sm = 0; sm < 4; ++sm)
            #pragma unroll
            for (int sn = 0; sn < 4; ++sn)
                acc[sm][sn] = __builtin_amdgcn_mfma_f32_16x16x32_bf16(
                                  a[sm], b[sn], acc[sm][sn], 0, 0, 0);
    }

    float* __restrict__ xpd = xp + (size_t)dir * T_LEN * GDIM;
    #pragma unroll
    for (int sn = 0; sn < 4; ++sn) {
        const int col  = j0 + wc + sn * 16 + r;
        const float bv = bi[col] + bh[col];
        #pragma unroll
        for (int sm = 0; sm < 4; ++sm) {
            #pragma unroll
            for (int j = 0; j < 4; ++j) {
                const int row = t0 + wr + sm * 16 + kg * 4 + j;
                xpd[(size_t)row * GDIM + col] = acc[sm][sn][j] + bv;
            }
        }
    }
}

// ============================================================================
// Kernel 2: cooperative persistent bidirectional LSTM scan.
// R11 exact structure (latched 4-load poll + s_sleep(1) -- empirically the
// only poll that sustains 12.9ms; R12's pipelined no-sleep poll cost +2.5ms).
// ONE addition: wave 0 raises priority (s_setprio) across the cell+publish
// window -- producer issues its transcendental chain + slot store ahead of
// the other 3 waves' poll traffic on the same CU (T5 role-split mechanism).
// ============================================================================
__global__ __launch_bounds__(256, 1)
void lstm_scan(const float* __restrict__ xp,
               const float* __restrict__ h0,
               const float* __restrict__ c0,
               const float* __restrict__ whh_f,
               const float* __restrict__ whh_b,
               float* __restrict__ hist,
               unsigned long long* __restrict__ slots)
{
    __shared__ float wsl[32][1024];   // 131072 B
    __shared__ float hbuf[1024];      //   4096 B
    __shared__ float gsh[32];

    const int tid = threadIdx.x;
    const int b   = blockIdx.x;
    const int dir = b & 1;            // XCD swizzle: fwd on even, bwd on odd
    const int bi  = b >> 1;
    const int u0  = bi * 8;
    const int rg  = tid >> 5;   // 0..7  (row group: 4 rows)
    const int kc  = tid & 31;   // 0..31 (k chunk)
    const int lrb = rg * 4;

    const float* __restrict__ whh = dir ? whh_b : whh_f;
    const size_t xpbase = (size_t)dir * T_LEN * GDIM;

    for (int lr = 0; lr < 32; ++lr) {
        const int grow = ((lr >> 3) << 10) + u0 + (lr & 7);
        *(float4*)&wsl[lr][tid * 4] = *(const float4*)&whh[(size_t)grow * H2DIM + tid * 4];
    }
    *(float4*)&hbuf[tid * 4] = *(const float4*)&h0[dir * H2DIM + tid * 4];
    float creg = 0.f;
    if (tid < 8) creg = c0[dir * H2DIM + u0 + tid];

    int grows[4];
    #pragma unroll
    for (int j = 0; j < 4; ++j) {
        const int lr = lrb + j;
        grows[j] = ((lr >> 3) << 10) + u0 + (lr & 7);
    }
    float xpc[4] = {0.f, 0.f, 0.f, 0.f};
    if (kc == 0) {
        #pragma unroll
        for (int j = 0; j < 4; ++j) xpc[j] = xp[xpbase + grows[j]];
    }
    __syncthreads();

    int budget = 4000000;

    for (int t = 0; t < T_LEN; ++t) {
        float xpn[4] = {0.f, 0.f, 0.f, 0.f};
        const int tnx = (t + 1 < T_LEN) ? (t + 1) : t;
        if (kc == 0) {
            #pragma unroll
            for (int j = 0; j < 4; ++j) xpn[j] = xp[xpbase + (size_t)tnx * GDIM + grows[j]];
        }

        float p0 = 0.f, p1 = 0.f, p2 = 0.f, p3 = 0.f;
        #pragma unroll
        for (int s = 0; s < 8; ++s) {
            const int ko = s * 128 + kc * 4;
            const float4 hv = *(const float4*)&hbuf[ko];
            const float4 w0 = *(const float4*)&wsl[lrb + 0][ko];
            const float4 w1 = *(const float4*)&wsl[lrb + 1][ko];
            const float4 w2 = *(const float4*)&wsl[lrb + 2][ko];
            const float4 w3 = *(const float4*)&wsl[lrb + 3][ko];
            p0 += w0.x*hv.x + w0.y*hv.y + w0.z*hv.z + w0.w*hv.w;
            p1 += w1.x*hv.x + w1.y*hv.y + w1.z*hv.z + w1.w*hv.w;
            p2 += w2.x*hv.x + w2.y*hv.y + w2.z*hv.z + w2.w*hv.w;
            p3 += w3.x*hv.x + w3.y*hv.y + w3.z*hv.z + w3.w*hv.w;
        }
        #pragma unroll
        for (int m = 16; m >= 1; m >>= 1) {
            p0 += __shfl_xor(p0, m);
            p1 += __shfl_xor(p1, m);
            p2 += __shfl_xor(p2, m);
            p3 += __shfl_xor(p3, m);
        }
        if (kc == 0) {
            gsh[lrb + 0] = p0 + xpc[0];
            gsh[lrb + 1] = p1 + xpc[1];
            gsh[lrb + 2] = p2 + xpc[2];
            gsh[lrb + 3] = p3 + xpc[3];
        }
        __syncthreads();

        // producer wave at raised priority across cell+publish (T5 role-split)
        if (tid < 64) __builtin_amdgcn_s_setprio(1);
        if (tid < 8) {
            const float gi = gsh[tid];
            const float gf = gsh[8 + tid];
            const float gg = gsh[16 + tid];
            const float go = gsh[24 + tid];
            const float c  = sigm(gf) * creg + sigm(gi) * tanhf(gg);
            const float h  = sigm(go) * tanhf(c);
            creg = c;
            const int tg = dir ? (T_LEN - 1 - t) : t;
            hist[(size_t)tg * 2048 + dir * H2DIM + u0 + tid] = h;
            const unsigned long long pack =
                ((unsigned long long)(unsigned)(t + 1) << 32) |
                (unsigned long long)__float_as_uint(h);
            __hip_atomic_store(&slots[((size_t)((t + 1) & 1) * 2 + dir) * H2DIM + u0 + tid],
                               pack, __ATOMIC_RELAXED, __HIP_MEMORY_SCOPE_AGENT);
        }
        if (tid < 64) __builtin_amdgcn_s_setprio(0);

        if (t + 1 < T_LEN) {
            const unsigned want = (unsigned)(t + 1);
            unsigned long long* sb = &slots[((size_t)((t + 1) & 1) * 2 + dir) * H2DIM + tid * 4];
            unsigned long long v0 = 0, v1 = 0, v2 = 0, v3 = 0;
            bool g0 = false, g1 = false, g2 = false, g3 = false;
            for (;;) {
                if (!g0) v0 = __hip_atomic_load(&sb[0], __ATOMIC_RELAXED, __HIP_MEMORY_SCOPE_AGENT);
                if (!g1) v1 = __hip_atomic_load(&sb[1], __ATOMIC_RELAXED, __HIP_MEMORY_SCOPE_AGENT);
                if (!g2) v2 = __hip_atomic_load(&sb[2], __ATOMIC_RELAXED, __HIP_MEMORY_SCOPE_AGENT);
                if (!g3) v3 = __hip_atomic_load(&sb[3], __ATOMIC_RELAXED, __HIP_MEMORY_SCOPE_AGENT);
                g0 = g0 || ((unsigned)(v0 >> 32) == want);
                g1 = g1 || ((unsigned)(v1 >> 32) == want);
                g2 = g2 || ((unsigned)(v2 >> 32) == want);
                g3 = g3 || ((unsigned)(v3 >> 32) == want);
                if (g0 && g1 && g2 && g3) break;
                if (--budget <= 0) break;                // hang-proof bail
                __builtin_amdgcn_s_sleep(1);             // throttle (required: R12 -2.5ms)
            }
            float4 hv;
            hv.x = __uint_as_float((unsigned)v0);
            hv.y = __uint_as_float((unsigned)v1);
            hv.z = __uint_as_float((unsigned)v2);
            hv.w = __uint_as_float((unsigned)v3);
            *(float4*)&hbuf[tid * 4] = hv;
        }
        __syncthreads();
        if (kc == 0) { xpc[0] = xpn[0]; xpc[1] = xpn[1]; xpc[2] = xpn[2]; xpc[3] = xpn[3]; }
    }
}

// ============================================================================
// Kernel 3: feats[t][n] = dot(hist[t], w_tag[n]) + b_tag[n]
// ============================================================================
__global__ __launch_bounds__(256)
void feats_kernel(const float* __restrict__ hist,
                  const float* __restrict__ w_tag,
                  const float* __restrict__ b_tag,
                  float* __restrict__ feats)
{
    const int t = blockIdx.x;
    const int tid = threadIdx.x;
    const float* __restrict__ hrow = hist + (size_t)t * 2048 + tid * 8;
    const float4 ha = *(const float4*)&hrow[0];
    const float4 hb = *(const float4*)&hrow[4];
    float p[4];
    #pragma unroll
    for (int n = 0; n < 4; ++n) {
        const float* __restrict__ wr = w_tag + n * 2048 + tid * 8;
        const float4 wa = *(const float4*)&wr[0];
        const float4 wb = *(const float4*)&wr[4];
        p[n] = ha.x*wa.x + ha.y*wa.y + ha.z*wa.z + ha.w*wa.w
             + hb.x*wb.x + hb.y*wb.y + hb.z*wb.z + hb.w*wb.w;
    }
    #pragma unroll
    for (int m = 32; m >= 1; m >>= 1) {
        #pragma unroll
        for (int n = 0; n < 4; ++n) p[n] += __shfl_down(p[n], m);
    }
    __shared__ float red[4][4];
    const int wv = tid >> 6;
    if ((tid & 63) == 0) {
        #pragma unroll
        for (int n = 0; n < 4; ++n) red[n][wv] = p[n];
    }
    __syncthreads();
    if (tid < 4)
        feats[(size_t)t * 4 + tid] = red[tid][0] + red[tid][1] + red[tid][2] + red[tid][3] + b_tag[tid];
}

// ============================================================================
// Kernel 4: Viterbi v2 (R10, unchanged; absmax=0 verified).
// ============================================================================
__global__ __launch_bounds__(256)
void viterbi_kernel(const float* __restrict__ feats,
                    const float* __restrict__ trans,
                    float* __restrict__ out)
{
    __shared__ float fsh[T_LEN * 4];   // 64 KB
    __shared__ unsigned bp[T_LEN];     // 16 KB
    __shared__ unsigned lmap[256];
    __shared__ unsigned smap[256];
    __shared__ int bestsh;
    const int tid = threadIdx.x;
    for (int i = tid; i < T_LEN; i += 256)
        *(float4*)&fsh[i * 4] = *(const float4*)&feats[(size_t)i * 4];
    __syncthreads();

    if (tid == 0) {
        float tr[16];
        #pragma unroll
        for (int i = 0; i < 16; ++i) tr[i] = trans[i];
        float fv[4] = {NEGV, NEGV, NEGV, NEGV};
        fv[START_TAG] = 0.0f;
        for (int t0 = 0; t0 < T_LEN; t0 += 8) {
            float4 f8[8];
            #pragma unroll
            for (int j = 0; j < 8; ++j) f8[j] = *(const float4*)&fsh[(t0 + j) * 4];
            #pragma unroll
            for (int j = 0; j < 8; ++j) {
                const float ft[4] = {f8[j].x, f8[j].y, f8[j].z, f8[j].w};
                float nf[4]; unsigned pb = 0;
                #pragma unroll
                for (int n = 0; n < 4; ++n) {
                    float m = fv[0] + tr[n * 4 + 0]; int bsel = 0;
                    #pragma unroll
                    for (int p = 1; p < 4; ++p) {
                        const float s = fv[p] + tr[n * 4 + p];
                        if (s > m) { m = s; bsel = p; }
                    }
                    nf[n] = m + ft[n];
                    pb |= (unsigned)bsel << (8 * n);
                }
                bp[t0 + j] = pb;
                fv[0] = nf[0]; fv[1] = nf[1]; fv[2] = nf[2]; fv[3] = nf[3];
            }
        }
        float bm = fv[0] + tr[STOP_TAG * 4 + 0]; int best = 0;
        #pragma unroll
        for (int p = 1; p < 4; ++p) {
            const float s = fv[p] + tr[STOP_TAG * 4 + p];
            if (s > bm) { bm = s; best = p; }
        }
        out[0] = bm;
        bestsh = best;
    }
    __syncthreads();

    const int c0 = tid * 16;
    unsigned L = bp[c0 + 15];
    #pragma unroll
    for (int j = 14; j >= 0; --j) L = compose4(bp[c0 + j], L);
    lmap[tid] = L;
    __syncthreads();
    if (tid == 0) {
        unsigned acc = 0x03020100u;              // identity map
        for (int i = 255; i >= 0; --i) { smap[i] = acc; acc = compose4(lmap[i], acc); }
    }
    __syncthreads();
    unsigned carry = smap[tid];
    const int best = bestsh;
    for (int t = c0 + 15; t >= c0; --t) {
        out[1 + t] = (float)((carry >> (8 * best)) & 3u);
        carry = compose4(bp[t], carry);
    }
}

// ============================================================================
extern "C" void kernel_launch(void* const* d_in, const int* in_sizes, int n_in,
                              void* d_out, int out_size, void* d_ws, size_t ws_size,
                              hipStream_t stream) {
    const float* x      = (const float*)d_in[0];
    const float* h0     = (const float*)d_in[1];
    const float* c0     = (const float*)d_in[2];
    const float* w_ih_f = (const float*)d_in[3];
    const float* w_hh_f = (const float*)d_in[4];
    const float* b_ih_f = (const float*)d_in[5];
    const float* b_hh_f = (const float*)d_in[6];
    const float* w_ih_b = (const float*)d_in[7];
    const float* w_hh_b = (const float*)d_in[8];
    const float* b_ih_b = (const float*)d_in[9];
    const float* b_hh_b = (const float*)d_in[10];
    const float* w_tag  = (const float*)d_in[11];
    const float* b_tag  = (const float*)d_in[12];
    const float* trans  = (const float*)d_in[13];
    float* out = (float*)d_out;

    if (ws_size < WS_NEED) return;   // signature: output stays poisoned

    char* ws = (char*)d_ws;
    float* xp    = (float*)(ws + XP_OFF);
    float* hist  = (float*)(ws + HIST_OFF);
    float* feats = (float*)(ws + FEATS_OFF);
    unsigned long long* slots = (unsigned long long*)(ws + SLOTS_OFF);
    unsigned short* xb  = (unsigned short*)(ws + XB_OFF);
    unsigned short* wbf = (unsigned short*)(ws + WBF_OFF);
    unsigned short* wbb = (unsigned short*)(ws + WBB_OFF);

    hipMemsetAsync(slots, 0, SLOTS_BYTES, stream);

    // fp32 -> bf16 staging for x, w_ih_f, w_ih_b in one launch (n4 = 1M each)
    const int n4 = (T_LEN * FDIM) / 4;
    conv_bf16x3<<<2048, 256, 0, stream>>>(x, xb, w_ih_f, wbf, w_ih_b, wbb, n4);

    // LDS-tiled bf16 MFMA input GEMM
    xp_gemm_mfma<<<dim3(1024, 2), 256, 0, stream>>>(
        xb, wbf, wbb, b_ih_f, b_hh_f, b_ih_b, b_hh_b, xp);

    // scan overwrites the hist region only after the gemm has consumed xb/wb*
    void* ka[] = { (void*)&xp, (void*)&h0, (void*)&c0, (void*)&w_hh_f, (void*)&w_hh_b,
                   (void*)&hist, (void*)&slots };
    hipLaunchCooperativeKernel((void*)lstm_scan, dim3(256), dim3(256), ka, 0, stream);

    feats_kernel<<<T_LEN, 256, 0, stream>>>(hist, w_tag, b_tag, feats);
    viterbi_kernel<<<1, 256, 0, stream>>>(feats, trans, out);
}